// Round 13
// baseline (579.982 us; speedup 1.0000x reference)
//
#include <hip/hip_runtime.h>
#include <hip/hip_bf16.h>

#define K30REV 4.77464829275686f   /* 30/(2*pi) */

typedef __attribute__((ext_vector_type(4))) float f32x4;
typedef __attribute__((ext_vector_type(8))) short s16x8;
typedef __attribute__((ext_vector_type(4))) unsigned u32x4;

__device__ __forceinline__ short f2bf(float f) {
    union { float f; unsigned u; } a; a.f = f;
    unsigned r = a.u + 0x7fffu + ((a.u >> 16) & 1u);
    return (short)(r >> 16);
}

__device__ __forceinline__ unsigned pk2(float a, float b) {
    union { __hip_bfloat162 h; unsigned u; } cv;
    cv.h = __float22bfloat162_rn(make_float2(a, b));
    return cv.u;
}

__device__ __forceinline__ s16x8 asfrag(u32x4 v) {
    union { u32x4 a; s16x8 b; } t; t.a = v; return t.b;
}

// sigma-permutation: MFMA D-slot (nt, q) -> original neuron index.
__device__ __forceinline__ int sigmaP(int nt, int q) {
    return (nt >> 1) * 32 + (q >> 2) * 8 + (nt & 1) * 4 + (q & 3);
}

// ---------- merged prep ----------
// wswz holds W * K30REV (scale folded into the GEMM); brev = bias * K30REV is
// consumed as the MFMA C-operand, so the activation is a bare sin(acc).
__global__ void k_prep(const float* __restrict__ ktraj,
                       const float* __restrict__ W0, const float* __restrict__ W1,
                       const float* __restrict__ W2, const float* __restrict__ W3,
                       const float* __restrict__ W4,
                       const float* __restrict__ b0, const float* __restrict__ b1,
                       const float* __restrict__ b2, const float* __restrict__ b3,
                       const float* __restrict__ Bmat,
                       float* __restrict__ tab, short* __restrict__ wswz,
                       short* __restrict__ w4f, float* __restrict__ brev,
                       float* __restrict__ ptx, float* __restrict__ pty,
                       float* __restrict__ ptz) {
    int i = blockIdx.x * 256 + threadIdx.x;
    if (i < 524288) {
        int n = i >> 8, s = i & 255;
        if (s < 128) {
            float a = ktraj[n] * (float)s;
            tab[n * 512 + s]       = __cosf(a);
            tab[n * 512 + 128 + s] = __sinf(a);
        } else {
            int y = s - 128;
            float a = ktraj[2048 + n] * (float)y;
            tab[n * 512 + 256 + y] = __cosf(a);
            tab[n * 512 + 384 + y] = __sinf(a);
        }
        return;
    }
    i -= 524288;
    if (i < 65536) {
        int layer = i >> 14, q14 = i & 16383;
        int nt = q14 >> 11, ks = (q14 >> 9) & 3;
        int ln = (q14 >> 3) & 63, j = i & 7;
        int orow = sigmaP(nt, ln & 15);
        int ocol = ks * 32 + (ln >> 4) * 8 + j;
        const float* src = (layer == 0) ? W0 : (layer == 1) ? W1 : (layer == 2) ? W2 : W3;
        wswz[i] = f2bf(src[orow * 128 + ocol] * K30REV);
        return;
    }
    i -= 65536;
    if (i < 2048) {
        // W4 fragments in wswz-style layout: w4f[ks*512 + lane*8 + j] (NOT scaled)
        int ks = i >> 9, ln = (i >> 3) & 63, j = i & 7;
        int row = ln & 15;                       // output col (only 0 valid)
        int col = ks * 32 + (ln >> 4) * 8 + j;   // k
        w4f[i] = f2bf(row == 0 ? W4[col] : 0.0f);
        return;
    }
    i -= 2048;
    if (i < 512) {
        int l = i >> 7, r = i & 127;
        int orow = sigmaP(r >> 4, r & 15);
        const float* src = (l == 0) ? b0 : (l == 1) ? b1 : (l == 2) ? b2 : b3;
        brev[i] = src[orow] * K30REV;
        return;
    }
    i -= 512;
    if (i < 8192) {             // ptx
        int x = i >> 6, e = i & 63;
        ptx[i] = ((x + 0.5f) * (1.0f / 128.0f)) * Bmat[e * 3 + 0];
        return;
    }
    i -= 8192;
    if (i < 8192) {             // pty
        int y = i >> 6, e = i & 63;
        pty[i] = ((y + 0.5f) * (1.0f / 128.0f)) * Bmat[e * 3 + 1];
        return;
    }
    i -= 8192;
    if (i < 4096) {             // ptz
        int z = i >> 6, e = i & 63;
        ptz[i] = ((z + 0.5f) * (1.0f / 64.0f)) * Bmat[e * 3 + 2];
    }
}

// one hidden layer, nt-pair software-pipelined; bias enters via MFMA C-operand
// at ks=0 (W prescaled by K30REV in prep) -> activation is bare sin(acc).
__device__ __forceinline__ void dolayer(const short* WL, const float* br,
                                        u32x4 (&SRC)[4][4], u32x4 (&DST)[4][4],
                                        s16x8 (&afA)[4], s16x8 (&afB)[4],
                                        const short* nextp) {
    #pragma unroll
    for (int nth = 0; nth < 4; nth++) {
        const int nt0 = 2 * nth, nt1 = 2 * nth + 1;
        f32x4 bb0 = *(const f32x4*)(br + nt0 * 16);
        f32x4 bb1 = *(const f32x4*)(br + nt1 * 16);
        // prefetch nt1 fragments (consumed after sins-nt0)
        #pragma unroll
        for (int ks = 0; ks < 4; ks++)
            afB[ks] = *(const s16x8*)(WL + nt1 * 2048 + ks * 512);
        // MFMA block nt0 (C-init = bias)
        f32x4 accA[4];
        #pragma unroll
        for (int ks = 0; ks < 4; ks++)
            #pragma unroll
            for (int rt = 0; rt < 4; rt++)
                accA[rt] = __builtin_amdgcn_mfma_f32_16x16x32_bf16(
                    afA[ks], asfrag(SRC[rt][ks]), (ks == 0) ? bb0 : accA[rt], 0, 0, 0);
        // sins nt0 -> DST[.][nth][0..1]
        #pragma unroll
        for (int rt = 0; rt < 4; rt++) {
            float a0 = __builtin_amdgcn_sinf(accA[rt][0]);
            float a1 = __builtin_amdgcn_sinf(accA[rt][1]);
            float a2 = __builtin_amdgcn_sinf(accA[rt][2]);
            float a3 = __builtin_amdgcn_sinf(accA[rt][3]);
            DST[rt][nth][0] = pk2(a0, a1);
            DST[rt][nth][1] = pk2(a2, a3);
        }
        // prefetch next even group / next-layer head / W4 fragments
        {
            const short* np = (nth < 3) ? (WL + (nt0 + 2) * 2048) : nextp;
            #pragma unroll
            for (int ks = 0; ks < 4; ks++)
                afA[ks] = *(const s16x8*)(np + ks * 512);
        }
        // MFMA block nt1 (C-init = bias)
        f32x4 accB[4];
        #pragma unroll
        for (int ks = 0; ks < 4; ks++)
            #pragma unroll
            for (int rt = 0; rt < 4; rt++)
                accB[rt] = __builtin_amdgcn_mfma_f32_16x16x32_bf16(
                    afB[ks], asfrag(SRC[rt][ks]), (ks == 0) ? bb1 : accB[rt], 0, 0, 0);
        // sins nt1 -> DST[.][nth][2..3]
        #pragma unroll
        for (int rt = 0; rt < 4; rt++) {
            float a0 = __builtin_amdgcn_sinf(accB[rt][0]);
            float a1 = __builtin_amdgcn_sinf(accB[rt][1]);
            float a2 = __builtin_amdgcn_sinf(accB[rt][2]);
            float a3 = __builtin_amdgcn_sinf(accB[rt][3]);
            DST[rt][nth][2] = pk2(a0, a1);
            DST[rt][nth][3] = pk2(a2, a3);
        }
    }
}

// ---------- kernel 1: register-resident SIREN, pipelined, 4 waves/SIMD ----------
__launch_bounds__(256, 4)
__global__ void k_siren(const float* __restrict__ ptx, const float* __restrict__ pty,
                        const float* __restrict__ ptz,
                        const float* __restrict__ brev,
                        const float* __restrict__ b4,
                        const short* __restrict__ wswz,
                        const short* __restrict__ w4f,
                        const float* __restrict__ image,
                        float* __restrict__ d_nat) {
    const int tid  = threadIdx.x;
    const int lane = tid & 63;
    const int w    = tid >> 6;
    const int l15  = lane & 15;
    const int l4   = lane >> 4;
    const int n0   = (blockIdx.x * 4 + w) * 64;
    const f32x4 zero4 = (f32x4){0.f, 0.f, 0.f, 0.f};

    u32x4 fragP[4][4], fragQ[4][4];
    s16x8 afA[4], afB[4];

    const short* WL0 = wswz + lane * 8;
    // preload layer-0 nt=0 fragments: latency fully hidden under encode
    #pragma unroll
    for (int ks = 0; ks < 4; ks++)
        afA[ks] = *(const s16x8*)(WL0 + ks * 512);

    // ---- encode directly into fragP ----
    {
        int x = n0 >> 13, y = (n0 >> 6) & 127;
        int e0 = l4 * 8;
        const float* px = ptx + x * 64 + e0;
        const float* py = pty + y * 64 + e0;
        f32x4 xa = *(const f32x4*)(px),      xb = *(const f32x4*)(px + 4);
        f32x4 xc = *(const f32x4*)(px + 32), xd = *(const f32x4*)(px + 36);
        f32x4 ya = *(const f32x4*)(py),      yb = *(const f32x4*)(py + 4);
        f32x4 yc = *(const f32x4*)(py + 32), yd = *(const f32x4*)(py + 36);
        float pxy[16];
        #pragma unroll
        for (int j = 0; j < 4; j++) {
            pxy[j]      = xa[j] + ya[j];
            pxy[4 + j]  = xb[j] + yb[j];
            pxy[8 + j]  = xc[j] + yc[j];
            pxy[12 + j] = xd[j] + yd[j];
        }
        #pragma unroll
        for (int rt = 0; rt < 4; rt++) {
            const float* pz = ptz + (rt * 16 + l15) * 64 + e0;
            f32x4 za = *(const f32x4*)(pz),      zb = *(const f32x4*)(pz + 4);
            f32x4 zc = *(const f32x4*)(pz + 32), zd = *(const f32x4*)(pz + 36);
            float s0[8], c0[8], s1[8], c1[8];
            #pragma unroll
            for (int j = 0; j < 4; j++) {
                float p0a = pxy[j] + za[j],      p0b = pxy[4 + j] + zb[j];
                float p1a = pxy[8 + j] + zc[j],  p1b = pxy[12 + j] + zd[j];
                s0[j]   = __builtin_amdgcn_sinf(p0a);  c0[j]   = __builtin_amdgcn_cosf(p0a);
                s0[4+j] = __builtin_amdgcn_sinf(p0b);  c0[4+j] = __builtin_amdgcn_cosf(p0b);
                s1[j]   = __builtin_amdgcn_sinf(p1a);  c1[j]   = __builtin_amdgcn_cosf(p1a);
                s1[4+j] = __builtin_amdgcn_sinf(p1b);  c1[4+j] = __builtin_amdgcn_cosf(p1b);
            }
            fragP[rt][0] = (u32x4){pk2(s0[0], s0[1]), pk2(s0[2], s0[3]),
                                   pk2(s0[4], s0[5]), pk2(s0[6], s0[7])};   // k = e
            fragP[rt][1] = (u32x4){pk2(s1[0], s1[1]), pk2(s1[2], s1[3]),
                                   pk2(s1[4], s1[5]), pk2(s1[6], s1[7])};   // k = 32+e
            fragP[rt][2] = (u32x4){pk2(c0[0], c0[1]), pk2(c0[2], c0[3]),
                                   pk2(c0[4], c0[5]), pk2(c0[6], c0[7])};   // k = 64+e
            fragP[rt][3] = (u32x4){pk2(c1[0], c1[1]), pk2(c1[2], c1[3]),
                                   pk2(c1[4], c1[5]), pk2(c1[6], c1[7])};   // k = 96+e
        }
    }

    // ---- 4 hidden layers, ping-pong P->Q->P->Q->P, prefetch chained ----
    dolayer(WL0,               brev + l4 * 4,       fragP, fragQ, afA, afB, WL0 + 16384);
    dolayer(WL0 + 16384,       brev + 128 + l4 * 4, fragQ, fragP, afA, afB, WL0 + 32768);
    dolayer(WL0 + 32768,       brev + 256 + l4 * 4, fragP, fragQ, afA, afB, WL0 + 49152);
    dolayer(WL0 + 49152,       brev + 384 + l4 * 4, fragQ, fragP, afA, afB, w4f + lane * 8);

    // ---- final layer: A-operand = fragP, B = W4 fragments (preloaded in afA) ----
    {
        f32x4 a4[4] = {zero4, zero4, zero4, zero4};
        #pragma unroll
        for (int ks = 0; ks < 4; ks++)
            #pragma unroll
            for (int rt = 0; rt < 4; rt++)
                a4[rt] = __builtin_amdgcn_mfma_f32_16x16x32_bf16(
                    asfrag(fragP[rt][ks]), afA[ks], a4[rt], 0, 0, 0);
        if (l15 == 0) {
            float b4v = b4[0];
            #pragma unroll
            for (int rt = 0; rt < 4; rt++) {
                int n = n0 + rt * 16 + l4 * 4;
                const f32x4 img = *(const f32x4*)(image + n);
                f32x4 dv;
                #pragma unroll
                for (int jj = 0; jj < 4; jj++) dv[jj] = a4[rt][jj] + b4v - img[jj];
                *(f32x4*)(d_nat + n) = dv;
            }
        }
    }
}

// ---------- kernel 1.5: d_nat [x][y][z] fp32 -> d_proj [z][x*128+y] bf16 ----------
__global__ void k_transpose(const float* __restrict__ d_nat, short* __restrict__ d_proj) {
    __shared__ float t[128][65];
    int x = blockIdx.x;
    for (int i = threadIdx.x; i < 8192; i += 256)
        t[i >> 6][i & 63] = d_nat[x * 8192 + i];
    __syncthreads();
    for (int i = threadIdx.x; i < 8192; i += 256) {
        int z = i >> 7, y = i & 127;
        d_proj[z * 16384 + x * 128 + y] = f2bf(t[y][z]);
    }
}

// ---------- kernel 2: NUDFT GEMM (M=64 z, N=2048 k-samples, K=16384 pixels) ----------
__launch_bounds__(256, 2)
__global__ void k_project(const short* __restrict__ d_proj, const float* __restrict__ tab,
                          float* __restrict__ part) {
    __shared__ alignas(16) float lt[4 * 32 * 132];
    const int tid  = threadIdx.x;
    const int lane = tid & 63;
    const int w    = tid >> 6;
    const int l15  = lane & 15;
    const int l4   = lane >> 4;
    const int nblk = blockIdx.x & 63;
    const int ksp  = blockIdx.x >> 6;
    const int nbase = nblk * 32;

    for (int i = tid; i < 16384; i += 256) {
        int nl = i >> 9, r = i & 511;
        int t = r >> 7, e = r & 127;
        lt[(t * 32 + nl) * 132 + e] = tab[(nbase + nl) * 512 + r];
    }
    __syncthreads();

    f32x4 ar[4][2], ai[4][2];
    #pragma unroll
    for (int rt = 0; rt < 4; rt++)
        #pragma unroll
        for (int nt = 0; nt < 2; nt++) {
            ar[rt][nt] = (f32x4){0.f, 0.f, 0.f, 0.f};
            ai[rt][nt] = (f32x4){0.f, 0.f, 0.f, 0.f};
        }

    const int p2base = ksp * 2048 + w * 512;
    #pragma unroll 1
    for (int ks = 0; ks < 16; ks++) {
        int p2c = p2base + ks * 32;
        s16x8 afr[4];
        #pragma unroll
        for (int rt = 0; rt < 4; rt++)
            afr[rt] = *(const s16x8*)(d_proj + (rt * 16 + l15) * 16384 + p2c + l4 * 8);
        int p2 = p2c + l4 * 8;
        int x = p2 >> 7, y0 = p2 & 127;
        #pragma unroll
        for (int nt = 0; nt < 2; nt++) {
            int nl = nt * 16 + l15;
            float cA = lt[nl * 132 + x];
            float sA = lt[(32 + nl) * 132 + x];
            const float* cB = &lt[(64 + nl) * 132 + y0];
            const float* sB = &lt[(96 + nl) * 132 + y0];
            s16x8 bc, bs;
            #pragma unroll
            for (int j = 0; j < 8; j++) {
                float cb = cB[j], sb = sB[j];
                bc[j] = f2bf(cA * cb - sA * sb);
                bs[j] = f2bf(sA * cb + cA * sb);
            }
            #pragma unroll
            for (int rt = 0; rt < 4; rt++) {
                ar[rt][nt] = __builtin_amdgcn_mfma_f32_16x16x32_bf16(afr[rt], bc, ar[rt][nt], 0, 0, 0);
                ai[rt][nt] = __builtin_amdgcn_mfma_f32_16x16x32_bf16(afr[rt], bs, ai[rt][nt], 0, 0, 0);
            }
        }
    }
    __syncthreads();
    float* red = lt;
    #pragma unroll
    for (int rt = 0; rt < 4; rt++)
        #pragma unroll
        for (int nt = 0; nt < 2; nt++)
            #pragma unroll
            for (int jj = 0; jj < 4; jj++) {
                int z = rt * 16 + l4 * 4 + jj;
                int q = nt * 16 + l15;
                red[(w * 64 + z) * 64 + q * 2 + 0] = ar[rt][nt][jj];
                red[(w * 64 + z) * 64 + q * 2 + 1] = ai[rt][nt][jj];
            }
    __syncthreads();
    for (int i = tid; i < 4096; i += 256) {
        int z = i >> 6, q = i & 63;
        float s = red[z * 64 + q] + red[4096 + z * 64 + q] + red[8192 + z * 64 + q] + red[12288 + z * 64 + q];
        part[((ksp * 64 + z) * 2048 + nbase + (q >> 1)) * 2 + (q & 1)] = s;
    }
}

// ---------- kernel 3: sum K-split partials, square, reduce to loss ----------
__global__ void k_loss(const float* __restrict__ part, float* __restrict__ out) {
    int g = blockIdx.x * 256 + threadIdx.x;
    int z = g >> 11, n = g & 2047;
    float r = 0.f, im = 0.f;
    #pragma unroll
    for (int ksp = 0; ksp < 8; ksp++) {
        const float2 v = *(const float2*)(part + ((ksp * 64 + z) * 2048 + n) * 2);
        r += v.x; im += v.y;
    }
    float val = r * r + im * im;
    #pragma unroll
    for (int o = 32; o > 0; o >>= 1) val += __shfl_xor(val, o);
    __shared__ float sred[4];
    if ((threadIdx.x & 63) == 0) sred[threadIdx.x >> 6] = val;
    __syncthreads();
    if (threadIdx.x == 0)
        atomicAdd(out, (sred[0] + sred[1] + sred[2] + sred[3]) * (0.5f / 131072.0f));
}

extern "C" void kernel_launch(void* const* d_in, const int* in_sizes, int n_in,
                              void* d_out, int out_size, void* d_ws, size_t ws_size,
                              hipStream_t stream) {
    const float* Bmat  = (const float*)d_in[1];
    const float* W0    = (const float*)d_in[2];
    const float* b0    = (const float*)d_in[3];
    const float* W1    = (const float*)d_in[4];
    const float* b1    = (const float*)d_in[5];
    const float* W2    = (const float*)d_in[6];
    const float* b2    = (const float*)d_in[7];
    const float* W3    = (const float*)d_in[8];
    const float* b3    = (const float*)d_in[9];
    const float* W4    = (const float*)d_in[10];
    const float* b4    = (const float*)d_in[11];
    const float* image = (const float*)d_in[12];
    const float* ktraj = (const float*)d_in[13];

    char* ws = (char*)d_ws;
    short* w4f    = (short*)(ws);                  // 4 KB (W4 in fragment layout)
    float* brev   = (float*)(ws + (8u << 10));     // 2 KB (sigma-permuted, prescaled)
    float* ptx    = (float*)(ws + (64u << 10));    // 32 KB
    float* pty    = (float*)(ws + (96u << 10));    // 32 KB
    float* ptz    = (float*)(ws + (128u << 10));   // 16 KB
    short* wswz   = (short*)(ws + (160u << 10));   // 128 KB (sigma-permuted, K30REV-prescaled)
    float* tab    = (float*)(ws + (1u << 20));     // 4 MB
    float* d_nat  = (float*)(ws + (5u << 20));     // 4 MB
    short* d_proj = (short*)(ws + (9u << 20));     // 2 MB
    float* part   = (float*)(ws + (11u << 20));    // 8 MB
    float* outf   = (float*)d_out;

    hipLaunchKernelGGL(k_prep,      dim3(2394), dim3(256), 0, stream,
                       ktraj, W0, W1, W2, W3, W4, b0, b1, b2, b3, Bmat,
                       tab, wswz, w4f, brev, ptx, pty, ptz);
    hipLaunchKernelGGL(k_siren,     dim3(4096), dim3(256), 0, stream,
                       ptx, pty, ptz, brev, b4, wswz, w4f, image, d_nat);
    hipLaunchKernelGGL(k_transpose, dim3(128),  dim3(256), 0, stream, d_nat, d_proj);
    hipLaunchKernelGGL(k_project,   dim3(512),  dim3(256), 0, stream, d_proj, tab, part);
    hipMemsetAsync(d_out, 0, sizeof(float), stream);
    hipLaunchKernelGGL(k_loss,      dim3(512),  dim3(256), 0, stream, part, outf);
}

// Round 14
// 186.675 us; speedup vs baseline: 3.1069x; 3.1069x over previous
//
#include <hip/hip_runtime.h>
#include <hip/hip_bf16.h>

#define K30REV 4.77464829275686f   /* 30/(2*pi) */

typedef __attribute__((ext_vector_type(4))) float f32x4;
typedef __attribute__((ext_vector_type(8))) short s16x8;
typedef __attribute__((ext_vector_type(4))) unsigned u32x4;

__device__ __forceinline__ short f2bf(float f) {
    union { float f; unsigned u; } a; a.f = f;
    unsigned r = a.u + 0x7fffu + ((a.u >> 16) & 1u);
    return (short)(r >> 16);
}

__device__ __forceinline__ unsigned pk2(float a, float b) {
    union { __hip_bfloat162 h; unsigned u; } cv;
    cv.h = __float22bfloat162_rn(make_float2(a, b));
    return cv.u;
}

__device__ __forceinline__ s16x8 asfrag(u32x4 v) {
    union { u32x4 a; s16x8 b; } t; t.a = v; return t.b;
}

// sigma-permutation: MFMA D-slot (nt, q) -> original neuron index.
__device__ __forceinline__ int sigmaP(int nt, int q) {
    return (nt >> 1) * 32 + (q >> 2) * 8 + (nt & 1) * 4 + (q & 3);
}

// ---------- merged prep ----------
// wswz holds W * K30REV (scale folded into the GEMM); brev = bias * K30REV is
// consumed as the MFMA C-operand, so the activation is a bare sin(acc).
__global__ void k_prep(const float* __restrict__ ktraj,
                       const float* __restrict__ W0, const float* __restrict__ W1,
                       const float* __restrict__ W2, const float* __restrict__ W3,
                       const float* __restrict__ W4,
                       const float* __restrict__ b0, const float* __restrict__ b1,
                       const float* __restrict__ b2, const float* __restrict__ b3,
                       const float* __restrict__ Bmat,
                       float* __restrict__ tab, short* __restrict__ wswz,
                       short* __restrict__ w4f, float* __restrict__ brev,
                       float* __restrict__ ptx, float* __restrict__ pty,
                       float* __restrict__ ptz) {
    int i = blockIdx.x * 256 + threadIdx.x;
    if (i < 524288) {
        int n = i >> 8, s = i & 255;
        if (s < 128) {
            float a = ktraj[n] * (float)s;
            tab[n * 512 + s]       = __cosf(a);
            tab[n * 512 + 128 + s] = __sinf(a);
        } else {
            int y = s - 128;
            float a = ktraj[2048 + n] * (float)y;
            tab[n * 512 + 256 + y] = __cosf(a);
            tab[n * 512 + 384 + y] = __sinf(a);
        }
        return;
    }
    i -= 524288;
    if (i < 65536) {
        int layer = i >> 14, q14 = i & 16383;
        int nt = q14 >> 11, ks = (q14 >> 9) & 3;
        int ln = (q14 >> 3) & 63, j = i & 7;
        int orow = sigmaP(nt, ln & 15);
        int ocol = ks * 32 + (ln >> 4) * 8 + j;
        const float* src = (layer == 0) ? W0 : (layer == 1) ? W1 : (layer == 2) ? W2 : W3;
        wswz[i] = f2bf(src[orow * 128 + ocol] * K30REV);
        return;
    }
    i -= 65536;
    if (i < 2048) {
        // W4 fragments in wswz-style layout: w4f[ks*512 + lane*8 + j] (NOT scaled)
        int ks = i >> 9, ln = (i >> 3) & 63, j = i & 7;
        int row = ln & 15;                       // output col (only 0 valid)
        int col = ks * 32 + (ln >> 4) * 8 + j;   // k
        w4f[i] = f2bf(row == 0 ? W4[col] : 0.0f);
        return;
    }
    i -= 2048;
    if (i < 512) {
        int l = i >> 7, r = i & 127;
        int orow = sigmaP(r >> 4, r & 15);
        const float* src = (l == 0) ? b0 : (l == 1) ? b1 : (l == 2) ? b2 : b3;
        brev[i] = src[orow] * K30REV;
        return;
    }
    i -= 512;
    if (i < 8192) {             // ptx
        int x = i >> 6, e = i & 63;
        ptx[i] = ((x + 0.5f) * (1.0f / 128.0f)) * Bmat[e * 3 + 0];
        return;
    }
    i -= 8192;
    if (i < 8192) {             // pty
        int y = i >> 6, e = i & 63;
        pty[i] = ((y + 0.5f) * (1.0f / 128.0f)) * Bmat[e * 3 + 1];
        return;
    }
    i -= 8192;
    if (i < 4096) {             // ptz
        int z = i >> 6, e = i & 63;
        ptz[i] = ((z + 0.5f) * (1.0f / 64.0f)) * Bmat[e * 3 + 2];
    }
}

// one hidden layer, nt-pair software-pipelined; bias enters via MFMA C-operand
// at ks=0 (W prescaled by K30REV in prep) -> activation is bare sin(acc).
__device__ __forceinline__ void dolayer(const short* WL, const float* br,
                                        u32x4 (&SRC)[4][4], u32x4 (&DST)[4][4],
                                        s16x8 (&afA)[4], s16x8 (&afB)[4],
                                        const short* nextp) {
    #pragma unroll
    for (int nth = 0; nth < 4; nth++) {
        const int nt0 = 2 * nth, nt1 = 2 * nth + 1;
        f32x4 bb0 = *(const f32x4*)(br + nt0 * 16);
        f32x4 bb1 = *(const f32x4*)(br + nt1 * 16);
        // prefetch nt1 fragments (consumed after sins-nt0)
        #pragma unroll
        for (int ks = 0; ks < 4; ks++)
            afB[ks] = *(const s16x8*)(WL + nt1 * 2048 + ks * 512);
        // MFMA block nt0 (C-init = bias)
        f32x4 accA[4];
        #pragma unroll
        for (int ks = 0; ks < 4; ks++)
            #pragma unroll
            for (int rt = 0; rt < 4; rt++)
                accA[rt] = __builtin_amdgcn_mfma_f32_16x16x32_bf16(
                    afA[ks], asfrag(SRC[rt][ks]), (ks == 0) ? bb0 : accA[rt], 0, 0, 0);
        // sins nt0 -> DST[.][nth][0..1]
        #pragma unroll
        for (int rt = 0; rt < 4; rt++) {
            float a0 = __builtin_amdgcn_sinf(accA[rt][0]);
            float a1 = __builtin_amdgcn_sinf(accA[rt][1]);
            float a2 = __builtin_amdgcn_sinf(accA[rt][2]);
            float a3 = __builtin_amdgcn_sinf(accA[rt][3]);
            DST[rt][nth][0] = pk2(a0, a1);
            DST[rt][nth][1] = pk2(a2, a3);
        }
        // prefetch next even group / next-layer head / W4 fragments
        {
            const short* np = (nth < 3) ? (WL + (nt0 + 2) * 2048) : nextp;
            #pragma unroll
            for (int ks = 0; ks < 4; ks++)
                afA[ks] = *(const s16x8*)(np + ks * 512);
        }
        // MFMA block nt1 (C-init = bias)
        f32x4 accB[4];
        #pragma unroll
        for (int ks = 0; ks < 4; ks++)
            #pragma unroll
            for (int rt = 0; rt < 4; rt++)
                accB[rt] = __builtin_amdgcn_mfma_f32_16x16x32_bf16(
                    afB[ks], asfrag(SRC[rt][ks]), (ks == 0) ? bb1 : accB[rt], 0, 0, 0);
        // sins nt1 -> DST[.][nth][2..3]
        #pragma unroll
        for (int rt = 0; rt < 4; rt++) {
            float a0 = __builtin_amdgcn_sinf(accB[rt][0]);
            float a1 = __builtin_amdgcn_sinf(accB[rt][1]);
            float a2 = __builtin_amdgcn_sinf(accB[rt][2]);
            float a3 = __builtin_amdgcn_sinf(accB[rt][3]);
            DST[rt][nth][2] = pk2(a0, a1);
            DST[rt][nth][3] = pk2(a2, a3);
        }
    }
}

// ---------- kernel 1: register-resident SIREN, pipelined (R12 shape, 2 waves/SIMD) ----------
__launch_bounds__(256, 2)
__global__ void k_siren(const float* __restrict__ ptx, const float* __restrict__ pty,
                        const float* __restrict__ ptz,
                        const float* __restrict__ brev,
                        const float* __restrict__ b4,
                        const short* __restrict__ wswz,
                        const short* __restrict__ w4f,
                        const float* __restrict__ image,
                        float* __restrict__ d_nat) {
    const int tid  = threadIdx.x;
    const int lane = tid & 63;
    const int w    = tid >> 6;
    const int l15  = lane & 15;
    const int l4   = lane >> 4;
    const int n0   = (blockIdx.x * 4 + w) * 64;
    const f32x4 zero4 = (f32x4){0.f, 0.f, 0.f, 0.f};

    u32x4 fragP[4][4], fragQ[4][4];
    s16x8 afA[4], afB[4];

    const short* WL0 = wswz + lane * 8;
    // preload layer-0 nt=0 fragments: latency fully hidden under encode
    #pragma unroll
    for (int ks = 0; ks < 4; ks++)
        afA[ks] = *(const s16x8*)(WL0 + ks * 512);

    // ---- encode directly into fragP ----
    {
        int x = n0 >> 13, y = (n0 >> 6) & 127;
        int e0 = l4 * 8;
        const float* px = ptx + x * 64 + e0;
        const float* py = pty + y * 64 + e0;
        f32x4 xa = *(const f32x4*)(px),      xb = *(const f32x4*)(px + 4);
        f32x4 xc = *(const f32x4*)(px + 32), xd = *(const f32x4*)(px + 36);
        f32x4 ya = *(const f32x4*)(py),      yb = *(const f32x4*)(py + 4);
        f32x4 yc = *(const f32x4*)(py + 32), yd = *(const f32x4*)(py + 36);
        float pxy[16];
        #pragma unroll
        for (int j = 0; j < 4; j++) {
            pxy[j]      = xa[j] + ya[j];
            pxy[4 + j]  = xb[j] + yb[j];
            pxy[8 + j]  = xc[j] + yc[j];
            pxy[12 + j] = xd[j] + yd[j];
        }
        #pragma unroll
        for (int rt = 0; rt < 4; rt++) {
            const float* pz = ptz + (rt * 16 + l15) * 64 + e0;
            f32x4 za = *(const f32x4*)(pz),      zb = *(const f32x4*)(pz + 4);
            f32x4 zc = *(const f32x4*)(pz + 32), zd = *(const f32x4*)(pz + 36);
            float s0[8], c0[8], s1[8], c1[8];
            #pragma unroll
            for (int j = 0; j < 4; j++) {
                float p0a = pxy[j] + za[j],      p0b = pxy[4 + j] + zb[j];
                float p1a = pxy[8 + j] + zc[j],  p1b = pxy[12 + j] + zd[j];
                s0[j]   = __builtin_amdgcn_sinf(p0a);  c0[j]   = __builtin_amdgcn_cosf(p0a);
                s0[4+j] = __builtin_amdgcn_sinf(p0b);  c0[4+j] = __builtin_amdgcn_cosf(p0b);
                s1[j]   = __builtin_amdgcn_sinf(p1a);  c1[j]   = __builtin_amdgcn_cosf(p1a);
                s1[4+j] = __builtin_amdgcn_sinf(p1b);  c1[4+j] = __builtin_amdgcn_cosf(p1b);
            }
            fragP[rt][0] = (u32x4){pk2(s0[0], s0[1]), pk2(s0[2], s0[3]),
                                   pk2(s0[4], s0[5]), pk2(s0[6], s0[7])};   // k = e
            fragP[rt][1] = (u32x4){pk2(s1[0], s1[1]), pk2(s1[2], s1[3]),
                                   pk2(s1[4], s1[5]), pk2(s1[6], s1[7])};   // k = 32+e
            fragP[rt][2] = (u32x4){pk2(c0[0], c0[1]), pk2(c0[2], c0[3]),
                                   pk2(c0[4], c0[5]), pk2(c0[6], c0[7])};   // k = 64+e
            fragP[rt][3] = (u32x4){pk2(c1[0], c1[1]), pk2(c1[2], c1[3]),
                                   pk2(c1[4], c1[5]), pk2(c1[6], c1[7])};   // k = 96+e
        }
    }

    // ---- 4 hidden layers, ping-pong P->Q->P->Q->P, prefetch chained ----
    dolayer(WL0,               brev + l4 * 4,       fragP, fragQ, afA, afB, WL0 + 16384);
    dolayer(WL0 + 16384,       brev + 128 + l4 * 4, fragQ, fragP, afA, afB, WL0 + 32768);
    dolayer(WL0 + 32768,       brev + 256 + l4 * 4, fragP, fragQ, afA, afB, WL0 + 49152);
    dolayer(WL0 + 49152,       brev + 384 + l4 * 4, fragQ, fragP, afA, afB, w4f + lane * 8);

    // ---- final layer: A-operand = fragP, B = W4 fragments (preloaded in afA) ----
    {
        f32x4 a4[4] = {zero4, zero4, zero4, zero4};
        #pragma unroll
        for (int ks = 0; ks < 4; ks++)
            #pragma unroll
            for (int rt = 0; rt < 4; rt++)
                a4[rt] = __builtin_amdgcn_mfma_f32_16x16x32_bf16(
                    asfrag(fragP[rt][ks]), afA[ks], a4[rt], 0, 0, 0);
        if (l15 == 0) {
            float b4v = b4[0];
            #pragma unroll
            for (int rt = 0; rt < 4; rt++) {
                int n = n0 + rt * 16 + l4 * 4;
                const f32x4 img = *(const f32x4*)(image + n);
                f32x4 dv;
                #pragma unroll
                for (int jj = 0; jj < 4; jj++) dv[jj] = a4[rt][jj] + b4v - img[jj];
                *(f32x4*)(d_nat + n) = dv;
            }
        }
    }
}

// ---------- kernel 1.5: d_nat [x][y][z] fp32 -> d_proj [z][x*128+y] bf16 ----------
__global__ void k_transpose(const float* __restrict__ d_nat, short* __restrict__ d_proj) {
    __shared__ float t[128][65];
    int x = blockIdx.x;
    for (int i = threadIdx.x; i < 8192; i += 256)
        t[i >> 6][i & 63] = d_nat[x * 8192 + i];
    __syncthreads();
    for (int i = threadIdx.x; i < 8192; i += 256) {
        int z = i >> 7, y = i & 127;
        d_proj[z * 16384 + x * 128 + y] = f2bf(t[y][z]);
    }
}

// ---------- kernel 2: NUDFT GEMM (M=64 z, N=2048 k-samples, K=16384 pixels) ----------
__launch_bounds__(256, 2)
__global__ void k_project(const short* __restrict__ d_proj, const float* __restrict__ tab,
                          float* __restrict__ part) {
    __shared__ alignas(16) float lt[4 * 32 * 132];
    const int tid  = threadIdx.x;
    const int lane = tid & 63;
    const int w    = tid >> 6;
    const int l15  = lane & 15;
    const int l4   = lane >> 4;
    const int nblk = blockIdx.x & 63;
    const int ksp  = blockIdx.x >> 6;
    const int nbase = nblk * 32;

    for (int i = tid; i < 16384; i += 256) {
        int nl = i >> 9, r = i & 511;
        int t = r >> 7, e = r & 127;
        lt[(t * 32 + nl) * 132 + e] = tab[(nbase + nl) * 512 + r];
    }
    __syncthreads();

    f32x4 ar[4][2], ai[4][2];
    #pragma unroll
    for (int rt = 0; rt < 4; rt++)
        #pragma unroll
        for (int nt = 0; nt < 2; nt++) {
            ar[rt][nt] = (f32x4){0.f, 0.f, 0.f, 0.f};
            ai[rt][nt] = (f32x4){0.f, 0.f, 0.f, 0.f};
        }

    const int p2base = ksp * 2048 + w * 512;
    #pragma unroll 1
    for (int ks = 0; ks < 16; ks++) {
        int p2c = p2base + ks * 32;
        s16x8 afr[4];
        #pragma unroll
        for (int rt = 0; rt < 4; rt++)
            afr[rt] = *(const s16x8*)(d_proj + (rt * 16 + l15) * 16384 + p2c + l4 * 8);
        int p2 = p2c + l4 * 8;
        int x = p2 >> 7, y0 = p2 & 127;
        #pragma unroll
        for (int nt = 0; nt < 2; nt++) {
            int nl = nt * 16 + l15;
            float cA = lt[nl * 132 + x];
            float sA = lt[(32 + nl) * 132 + x];
            const float* cB = &lt[(64 + nl) * 132 + y0];
            const float* sB = &lt[(96 + nl) * 132 + y0];
            s16x8 bc, bs;
            #pragma unroll
            for (int j = 0; j < 8; j++) {
                float cb = cB[j], sb = sB[j];
                bc[j] = f2bf(cA * cb - sA * sb);
                bs[j] = f2bf(sA * cb + cA * sb);
            }
            #pragma unroll
            for (int rt = 0; rt < 4; rt++) {
                ar[rt][nt] = __builtin_amdgcn_mfma_f32_16x16x32_bf16(afr[rt], bc, ar[rt][nt], 0, 0, 0);
                ai[rt][nt] = __builtin_amdgcn_mfma_f32_16x16x32_bf16(afr[rt], bs, ai[rt][nt], 0, 0, 0);
            }
        }
    }
    __syncthreads();
    float* red = lt;
    #pragma unroll
    for (int rt = 0; rt < 4; rt++)
        #pragma unroll
        for (int nt = 0; nt < 2; nt++)
            #pragma unroll
            for (int jj = 0; jj < 4; jj++) {
                int z = rt * 16 + l4 * 4 + jj;
                int q = nt * 16 + l15;
                red[(w * 64 + z) * 64 + q * 2 + 0] = ar[rt][nt][jj];
                red[(w * 64 + z) * 64 + q * 2 + 1] = ai[rt][nt][jj];
            }
    __syncthreads();
    for (int i = tid; i < 4096; i += 256) {
        int z = i >> 6, q = i & 63;
        float s = red[z * 64 + q] + red[4096 + z * 64 + q] + red[8192 + z * 64 + q] + red[12288 + z * 64 + q];
        part[((ksp * 64 + z) * 2048 + nbase + (q >> 1)) * 2 + (q & 1)] = s;
    }
}

// ---------- kernel 3: sum K-split partials, square, reduce to loss ----------
__global__ void k_loss(const float* __restrict__ part, float* __restrict__ out) {
    int g = blockIdx.x * 256 + threadIdx.x;
    int z = g >> 11, n = g & 2047;
    float r = 0.f, im = 0.f;
    #pragma unroll
    for (int ksp = 0; ksp < 8; ksp++) {
        const float2 v = *(const float2*)(part + ((ksp * 64 + z) * 2048 + n) * 2);
        r += v.x; im += v.y;
    }
    float val = r * r + im * im;
    #pragma unroll
    for (int o = 32; o > 0; o >>= 1) val += __shfl_xor(val, o);
    __shared__ float sred[4];
    if ((threadIdx.x & 63) == 0) sred[threadIdx.x >> 6] = val;
    __syncthreads();
    if (threadIdx.x == 0)
        atomicAdd(out, (sred[0] + sred[1] + sred[2] + sred[3]) * (0.5f / 131072.0f));
}

extern "C" void kernel_launch(void* const* d_in, const int* in_sizes, int n_in,
                              void* d_out, int out_size, void* d_ws, size_t ws_size,
                              hipStream_t stream) {
    const float* Bmat  = (const float*)d_in[1];
    const float* W0    = (const float*)d_in[2];
    const float* b0    = (const float*)d_in[3];
    const float* W1    = (const float*)d_in[4];
    const float* b1    = (const float*)d_in[5];
    const float* W2    = (const float*)d_in[6];
    const float* b2    = (const float*)d_in[7];
    const float* W3    = (const float*)d_in[8];
    const float* b3    = (const float*)d_in[9];
    const float* W4    = (const float*)d_in[10];
    const float* b4    = (const float*)d_in[11];
    const float* image = (const float*)d_in[12];
    const float* ktraj = (const float*)d_in[13];

    char* ws = (char*)d_ws;
    short* w4f    = (short*)(ws);                  // 4 KB (W4 in fragment layout)
    float* brev   = (float*)(ws + (8u << 10));     // 2 KB (sigma-permuted, prescaled)
    float* ptx    = (float*)(ws + (64u << 10));    // 32 KB
    float* pty    = (float*)(ws + (96u << 10));    // 32 KB
    float* ptz    = (float*)(ws + (128u << 10));   // 16 KB
    short* wswz   = (short*)(ws + (160u << 10));   // 128 KB (sigma-permuted, K30REV-prescaled)
    float* tab    = (float*)(ws + (1u << 20));     // 4 MB
    float* d_nat  = (float*)(ws + (5u << 20));     // 4 MB
    short* d_proj = (short*)(ws + (9u << 20));     // 2 MB
    float* part   = (float*)(ws + (11u << 20));    // 8 MB
    float* outf   = (float*)d_out;

    hipLaunchKernelGGL(k_prep,      dim3(2394), dim3(256), 0, stream,
                       ktraj, W0, W1, W2, W3, W4, b0, b1, b2, b3, Bmat,
                       tab, wswz, w4f, brev, ptx, pty, ptz);
    hipLaunchKernelGGL(k_siren,     dim3(4096), dim3(256), 0, stream,
                       ptx, pty, ptz, brev, b4, wswz, w4f, image, d_nat);
    hipLaunchKernelGGL(k_transpose, dim3(128),  dim3(256), 0, stream, d_nat, d_proj);
    hipLaunchKernelGGL(k_project,   dim3(512),  dim3(256), 0, stream, d_proj, tab, part);
    hipMemsetAsync(d_out, 0, sizeof(float), stream);
    hipLaunchKernelGGL(k_loss,      dim3(512),  dim3(256), 0, stream, part, outf);
}